// Round 1
// baseline (57.773 us; speedup 1.0000x reference)
//
#include <hip/hip_runtime.h>

#define D_K   128
#define SEQ   2048
#define NPAIR 64   // D_K / 2

// ---------------------------------------------------------------------------
// Kernel 1: gather (cos, sin) per (s, k) from the block-diagonal rotation
// buffer into a compact 1 MiB table in workspace.
//   rot[pos, 2k,   2k] =  cos
//   rot[pos, 2k+1, 2k] =  sin
// tab[s*NPAIR + k] = (cos, sin)
// ---------------------------------------------------------------------------
__global__ void rope_gather_kernel(const float* __restrict__ rot,
                                   const int* __restrict__ pos,
                                   float2* __restrict__ tab) {
    int idx = blockIdx.x * blockDim.x + threadIdx.x;   // s*64 + k
    if (idx >= SEQ * NPAIR) return;
    int k = idx & (NPAIR - 1);
    int s = idx >> 6;
    long long p = (long long)pos[s];
    const float* base = rot + p * (long long)(D_K * D_K);
    float c  = base[(2 * k)     * D_K + 2 * k];
    float sn = base[(2 * k + 1) * D_K + 2 * k];
    tab[idx] = make_float2(c, sn);
}

// ---------------------------------------------------------------------------
// Kernel 2: elementwise rotation, vectorized float4 (16 B/lane).
// One float4 of x = elements (2k0, 2k0+1, 2k0+2, 2k0+3) -> 2 pairs.
// tab viewed as float4: tab4[s*32 + i4] = (cos0, sin0, cos1, sin1).
// ---------------------------------------------------------------------------
__global__ void rope_apply_kernel(const float4* __restrict__ x,
                                  const float4* __restrict__ tab4,
                                  float4* __restrict__ out,
                                  int total4) {
    int stride = gridDim.x * blockDim.x;
    for (int idx = blockIdx.x * blockDim.x + threadIdx.x; idx < total4;
         idx += stride) {
        int i4 = idx & 31;                 // 32 float4 per d_k row
        int s  = (idx >> 5) & (SEQ - 1);   // sequence index
        float4 xv = x[idx];
        float4 cs = tab4[s * 32 + i4];
        float4 o;
        o.x = cs.x * xv.x - cs.y * xv.y;
        o.y = cs.y * xv.x + cs.x * xv.y;
        o.z = cs.z * xv.z - cs.w * xv.w;
        o.w = cs.w * xv.z + cs.z * xv.w;
        out[idx] = o;
    }
}

// ---------------------------------------------------------------------------
// Fallback: fused gather+apply (no workspace needed). Only used if ws_size
// is too small for the 1 MiB table.
// ---------------------------------------------------------------------------
__global__ void rope_fused_kernel(const float4* __restrict__ x,
                                  const float* __restrict__ rot,
                                  const int* __restrict__ pos,
                                  float4* __restrict__ out,
                                  int total4) {
    int stride = gridDim.x * blockDim.x;
    for (int idx = blockIdx.x * blockDim.x + threadIdx.x; idx < total4;
         idx += stride) {
        int i4 = idx & 31;
        int s  = (idx >> 5) & (SEQ - 1);
        int e0 = i4 * 4;                   // first even element of the float4
        long long p = (long long)pos[s];
        const float* base = rot + p * (long long)(D_K * D_K);
        float c0 = base[(e0)     * D_K + e0];
        float s0 = base[(e0 + 1) * D_K + e0];
        float c1 = base[(e0 + 2) * D_K + e0 + 2];
        float s1 = base[(e0 + 3) * D_K + e0 + 2];
        float4 xv = x[idx];
        float4 o;
        o.x = c0 * xv.x - s0 * xv.y;
        o.y = s0 * xv.x + c0 * xv.y;
        o.z = c1 * xv.z - s1 * xv.w;
        o.w = s1 * xv.z + c1 * xv.w;
        out[idx] = o;
    }
}

extern "C" void kernel_launch(void* const* d_in, const int* in_sizes, int n_in,
                              void* d_out, int out_size, void* d_ws, size_t ws_size,
                              hipStream_t stream) {
    const float* x   = (const float*)d_in[0];   // [8,16,2048,128] f32
    const int*   pos = (const int*)d_in[1];     // [2048] int32
    const float* rot = (const float*)d_in[2];   // [2048,128,128] f32
    float*       out = (float*)d_out;

    int total  = in_sizes[0];                   // 33,554,432
    int total4 = total / 4;                     // 8,388,608 float4s

    const size_t tab_bytes = (size_t)SEQ * NPAIR * sizeof(float2); // 1 MiB

    // apply-kernel grid: 2048 blocks x 256 threads, grid-stride (16 iters/thread)
    int ablocks = 2048;

    if (ws_size >= tab_bytes) {
        float2* tab = (float2*)d_ws;
        int gthreads = SEQ * NPAIR;             // 131,072
        rope_gather_kernel<<<(gthreads + 255) / 256, 256, 0, stream>>>(
            rot, pos, tab);
        rope_apply_kernel<<<ablocks, 256, 0, stream>>>(
            (const float4*)x, (const float4*)tab, (float4*)out, total4);
    } else {
        rope_fused_kernel<<<ablocks, 256, 0, stream>>>(
            (const float4*)x, rot, pos, (float4*)out, total4);
    }
}

// Round 3
// 49.980 us; speedup vs baseline: 1.1559x; 1.1559x over previous
//
#include <hip/hip_runtime.h>

#define D_K    128
#define SEQ    2048
#define NPAIR  64   // D_K / 2
#define UNROLL 4

// native vector type (works with __builtin_nontemporal_store, unlike HIP float4)
typedef float f32x4 __attribute__((ext_vector_type(4)));

// ---------------------------------------------------------------------------
// Kernel 1: gather (cos, sin) per (s, k) from the block-diagonal rotation
// buffer into a compact 1 MiB table in workspace.
//   rot[pos, 2k,   2k] =  cos
//   rot[pos, 2k+1, 2k] =  sin
// tab[s*NPAIR + k] = (cos, sin)
// ---------------------------------------------------------------------------
__global__ void rope_gather_kernel(const float* __restrict__ rot,
                                   const int* __restrict__ pos,
                                   float2* __restrict__ tab) {
    int idx = blockIdx.x * blockDim.x + threadIdx.x;   // s*64 + k
    if (idx >= SEQ * NPAIR) return;
    int k = idx & (NPAIR - 1);
    int s = idx >> 6;
    long long p = (long long)pos[s];
    const float* base = rot + p * (long long)(D_K * D_K);
    float c  = base[(2 * k)     * D_K + 2 * k];
    float sn = base[(2 * k + 1) * D_K + 2 * k];
    tab[idx] = make_float2(c, sn);
}

// ---------------------------------------------------------------------------
// Kernel 2: elementwise rotation. Exact-size launch: each thread handles
// UNROLL independent float4s (64 B in flight), no loop, no bounds checks.
// Independent loads back-to-back -> 4 outstanding VMEM ops/lane to hide
// HBM latency (the R1 kernel had 1 -> latency-bound at 2.5 TB/s).
// Non-temporal stores keep the streaming output from evicting x in L3.
// ---------------------------------------------------------------------------
__global__ __launch_bounds__(256) void rope_apply_kernel(
        const f32x4* __restrict__ x,
        const f32x4* __restrict__ tab4,
        f32x4* __restrict__ out) {
    int gid    = blockIdx.x * blockDim.x + threadIdx.x;
    int stride = gridDim.x * blockDim.x;

    int   idx[UNROLL];
    f32x4 xv[UNROLL];
    f32x4 cs[UNROLL];
#pragma unroll
    for (int j = 0; j < UNROLL; ++j) {
        idx[j] = gid + j * stride;
        xv[j]  = x[idx[j]];
        cs[j]  = tab4[(((idx[j] >> 5) & (SEQ - 1)) << 5) + (idx[j] & 31)];
    }
#pragma unroll
    for (int j = 0; j < UNROLL; ++j) {
        f32x4 o;
        o.x = cs[j].x * xv[j].x - cs[j].y * xv[j].y;
        o.y = cs[j].y * xv[j].x + cs[j].x * xv[j].y;
        o.z = cs[j].z * xv[j].z - cs[j].w * xv[j].w;
        o.w = cs[j].w * xv[j].z + cs[j].z * xv[j].w;
        __builtin_nontemporal_store(o, &out[idx[j]]);
    }
}

// ---------------------------------------------------------------------------
// Grid-stride fallback (handles any size / tiny workspace). Fused gather.
// ---------------------------------------------------------------------------
__global__ void rope_fused_kernel(const f32x4* __restrict__ x,
                                  const float* __restrict__ rot,
                                  const int* __restrict__ pos,
                                  f32x4* __restrict__ out,
                                  int total4) {
    int stride = gridDim.x * blockDim.x;
    for (int idx = blockIdx.x * blockDim.x + threadIdx.x; idx < total4;
         idx += stride) {
        int i4 = idx & 31;
        int s  = (idx >> 5) & (SEQ - 1);
        int e0 = i4 * 4;
        long long p = (long long)pos[s];
        const float* base = rot + p * (long long)(D_K * D_K);
        float c0 = base[(e0)     * D_K + e0];
        float s0 = base[(e0 + 1) * D_K + e0];
        float c1 = base[(e0 + 2) * D_K + e0 + 2];
        float s1 = base[(e0 + 3) * D_K + e0 + 2];
        f32x4 xv = x[idx];
        f32x4 o;
        o.x = c0 * xv.x - s0 * xv.y;
        o.y = s0 * xv.x + c0 * xv.y;
        o.z = c1 * xv.z - s1 * xv.w;
        o.w = s1 * xv.z + c1 * xv.w;
        out[idx] = o;
    }
}

extern "C" void kernel_launch(void* const* d_in, const int* in_sizes, int n_in,
                              void* d_out, int out_size, void* d_ws, size_t ws_size,
                              hipStream_t stream) {
    const float* x   = (const float*)d_in[0];   // [8,16,2048,128] f32
    const int*   pos = (const int*)d_in[1];     // [2048] int32
    const float* rot = (const float*)d_in[2];   // [2048,128,128] f32
    float*       out = (float*)d_out;

    int total  = in_sizes[0];                   // 33,554,432
    int total4 = total / 4;                     // 8,388,608 float4s

    const size_t tab_bytes = (size_t)SEQ * NPAIR * sizeof(float2); // 1 MiB
    const int    tpb       = 256;
    const int    per_block = tpb * UNROLL;      // 1024 float4s / block

    if (ws_size >= tab_bytes && (total4 % per_block) == 0) {
        float2* tab = (float2*)d_ws;
        int gthreads = SEQ * NPAIR;             // 131,072
        rope_gather_kernel<<<(gthreads + 255) / 256, 256, 0, stream>>>(
            rot, pos, tab);
        rope_apply_kernel<<<total4 / per_block, tpb, 0, stream>>>(
            (const f32x4*)x, (const f32x4*)tab, (f32x4*)out);
    } else {
        rope_fused_kernel<<<2048, tpb, 0, stream>>>(
            (const f32x4*)x, rot, pos, (f32x4*)out, total4);
    }
}

// Round 4
// 43.789 us; speedup vs baseline: 1.3194x; 1.1414x over previous
//
#include <hip/hip_runtime.h>
#include <math.h>

#define D_K    128
#define SEQ    2048
#define SLAB   65536   // float4s per (b,h) slab: 2048 rows * 32 float4
#define UNROLL 8       // one thread: same (s,i4) across 8 consecutive slabs

// native vector type (works with __builtin_nontemporal_store)
typedef float f32x4 __attribute__((ext_vector_type(4)));

// ---------------------------------------------------------------------------
// Fused RoPE: out[b,h,s,:] = R(pos[s]) @ x[b,h,s,:], R block-diagonal 2x2.
// Thread layout: gid & 65535 -> (s, i4) inside a slab; gid >> 16 -> group of
// UNROLL slabs. The (cos,sin) pair for (s, i4) is computed ONCE and reused
// for all UNROLL float4s (previous version paid 1 table load per float4).
// 8 independent 16B loads in flight per lane hide HBM latency; nt stores
// keep the streaming output from evicting x in L3.
// ---------------------------------------------------------------------------
__global__ __launch_bounds__(256) void rope_fused8_kernel(
        const f32x4* __restrict__ x,
        const int* __restrict__ pos,
        f32x4* __restrict__ out) {
    int gid   = blockIdx.x * 256 + threadIdx.x;
    int local = gid & (SLAB - 1);             // (s, i4) within a slab
    int grp   = gid >> 16;                    // which group of UNROLL slabs
    int base  = local + grp * (UNROLL * SLAB);

    int s  = local >> 5;                      // sequence row
    int i4 = local & 31;                      // float4 within the d_k row
    float p = (float)pos[s];

    // pair indices 2*i4, 2*i4+1; inv_freq = 10000^(-kp/64) = 2^(C*kp)
    const float C = -0.20762050593046016f;    // -log2(10000)/64
    float f0 = exp2f(C * (float)(2 * i4));
    float f1 = exp2f(C * (float)(2 * i4 + 1));
    float s0, c0, s1, c1;
    sincosf(p * f0, &s0, &c0);
    sincosf(p * f1, &s1, &c1);

    f32x4 xv[UNROLL];
#pragma unroll
    for (int j = 0; j < UNROLL; ++j) xv[j] = x[base + j * SLAB];

#pragma unroll
    for (int j = 0; j < UNROLL; ++j) {
        f32x4 o;
        o.x = c0 * xv[j].x - s0 * xv[j].y;
        o.y = s0 * xv[j].x + c0 * xv[j].y;
        o.z = c1 * xv[j].z - s1 * xv[j].w;
        o.w = s1 * xv[j].z + c1 * xv[j].w;
        __builtin_nontemporal_store(o, &out[base + j * SLAB]);
    }
}

// ---------------------------------------------------------------------------
// Generic grid-stride fallback (any size): gathers cos/sin from rotate_m.
// ---------------------------------------------------------------------------
__global__ void rope_fused_kernel(const f32x4* __restrict__ x,
                                  const float* __restrict__ rot,
                                  const int* __restrict__ pos,
                                  f32x4* __restrict__ out,
                                  int total4) {
    int stride = gridDim.x * blockDim.x;
    for (int idx = blockIdx.x * blockDim.x + threadIdx.x; idx < total4;
         idx += stride) {
        int i4 = idx & 31;
        int s  = (idx >> 5) & (SEQ - 1);
        int e0 = i4 * 4;
        long long p = (long long)pos[s];
        const float* base = rot + p * (long long)(D_K * D_K);
        float c0 = base[(e0)     * D_K + e0];
        float s0 = base[(e0 + 1) * D_K + e0];
        float c1 = base[(e0 + 2) * D_K + e0 + 2];
        float s1 = base[(e0 + 3) * D_K + e0 + 2];
        f32x4 xv = x[idx];
        f32x4 o;
        o.x = c0 * xv.x - s0 * xv.y;
        o.y = s0 * xv.x + c0 * xv.y;
        o.z = c1 * xv.z - s1 * xv.w;
        o.w = s1 * xv.z + c1 * xv.w;
        out[idx] = o;
    }
}

extern "C" void kernel_launch(void* const* d_in, const int* in_sizes, int n_in,
                              void* d_out, int out_size, void* d_ws, size_t ws_size,
                              hipStream_t stream) {
    const float* x   = (const float*)d_in[0];   // [8,16,2048,128] f32
    const int*   pos = (const int*)d_in[1];     // [2048] int32
    const float* rot = (const float*)d_in[2];   // [2048,128,128] f32
    float*       out = (float*)d_out;

    int total  = in_sizes[0];                   // 33,554,432
    int total4 = total / 4;                     // 8,388,608 float4s

    if (total4 == 128 * SLAB) {                 // exact problem shape
        int threads = total4 / UNROLL;          // 1,048,576
        rope_fused8_kernel<<<threads / 256, 256, 0, stream>>>(
            (const f32x4*)x, pos, (f32x4*)out);
    } else {
        rope_fused_kernel<<<2048, 256, 0, stream>>>(
            (const f32x4*)x, rot, pos, (f32x4*)out, total4);
    }
}